// Round 4
// baseline (362.805 us; speedup 1.0000x reference)
//
#include <hip/hip_runtime.h>
#include <stdint.h>

typedef unsigned int u32;
typedef __attribute__((ext_vector_type(8))) __bf16 bf16x8;
typedef __attribute__((ext_vector_type(8))) short s16x8;
typedef __attribute__((ext_vector_type(4))) short s16x4;
typedef __attribute__((ext_vector_type(4))) float f32x4;

// ---------- helpers ----------

__device__ __forceinline__ short f2bf(float f) {
    __bf16 h = (__bf16)f;               // native v_cvt, RNE
    return __builtin_bit_cast(short, h);
}

__device__ __forceinline__ bf16x8 asbf(s16x8 v) {
    return __builtin_bit_cast(bf16x8, v);
}

// async global->LDS, 16B per lane (attn only)
__device__ __forceinline__ void gl_lds16(const void* g, void* l) {
    __builtin_amdgcn_global_load_lds((__attribute__((address_space(1))) u32*)g,
                                     (__attribute__((address_space(3))) u32*)l,
                                     16, 0, 0);
}

// ---------- conversion kernel: fp32 -> bf16 ----------

__global__ __launch_bounds__(256) void convert_all(
    const float* __restrict__ s0, short* __restrict__ d0,
    const float* __restrict__ s1, short* __restrict__ d1,
    const float* __restrict__ s2, short* __restrict__ d2,
    const float* __restrict__ s3, short* __restrict__ d3,
    const float* __restrict__ s4, short* __restrict__ d4,
    const float* __restrict__ s5, short* __restrict__ d5)
{
    int i = blockIdx.x * 256 + threadIdx.x;   // one float4 per thread
    const float* s; short* d;
    if (i < 786432)                { s = s0; d = d0; }
    else if ((i -= 786432) < 786432) { s = s1; d = d1; }
    else if ((i -= 786432) < 442368) { s = s2; d = d2; }
    else if ((i -= 442368) < 442368) { s = s3; d = d3; }
    else if ((i -= 442368) < 147456) { s = s4; d = d4; }
    else                           { i -= 147456; s = s5; d = d5; }
    f32x4 v = ((const f32x4*)s)[i];
    s16x4 o;
    o.x = f2bf(v.x); o.y = f2bf(v.y); o.z = f2bf(v.z); o.w = f2bf(v.w);
    ((s16x4*)d)[i] = o;
}

// ---------- QKV GEMM v4 (M=4096, N=2304, K=768) ----------
// LDS-free, barrier-free: each wave loads its MFMA fragments directly from
// global (the global access pattern IS the fragment layout). K-chunk 32,
// two-stage register pipeline; compiler schedules fine-grained vmcnt.
// XCD-swizzled flat grid: bid&7 = XCD, each XCD owns a 4-m-block stripe.
// Epilogue: bias + per-head LN, transpose via per-wave LDS, coalesced stores.

__global__ __launch_bounds__(256, 2) void qkv_gemm(
    const short* __restrict__ Ax, const short* __restrict__ Ay,
    const short* __restrict__ Wx, const short* __restrict__ Wy,
    const float* __restrict__ biasx, const float* __restrict__ biasy,
    const float* __restrict__ gqx, const float* __restrict__ bqx,
    const float* __restrict__ gkx, const float* __restrict__ bkx,
    const float* __restrict__ gqy, const float* __restrict__ bqy,
    const float* __restrict__ gky, const float* __restrict__ bky,
    short* __restrict__ Q, short* __restrict__ K, short* __restrict__ Vt)
{
    __shared__ __align__(16) short lE[4][5120];   // per-wave epilogue transpose, stride 80
    const int tid  = threadIdx.x;
    const int w    = tid >> 6, lane = tid & 63;
    const int lam  = lane & 15, quad = lane >> 4;

    // grid decode: 1152 blocks. xcd-stripe over m.
    const int bid  = blockIdx.x;
    const int xcd  = bid & 7;
    const int slot = bid >> 3;            // 0..143
    const int mloc = slot & 3;
    const int r2   = slot >> 2;           // 0..35
    const int nblk = r2 % 18;
    const int strm = r2 / 18;
    const int m0   = (xcd * 4 + mloc) * 128;
    const int n0   = nblk * 128;

    const short* A    = strm ? Ay : Ax;
    const short* W    = strm ? Wy : Wx;
    const float* bias = strm ? biasy : biasx;
    const int wm = w >> 1, wn = w & 1;

    // per-lane fragment base pointers (quad*8 folded in)
    const short* Arow[4];
    const short* Wrow[4];
    #pragma unroll
    for (int i = 0; i < 4; i++)
        Arow[i] = A + (size_t)(m0 + wm * 64 + i * 16 + lam) * 768 + quad * 8;
    #pragma unroll
    for (int t = 0; t < 4; t++)
        Wrow[t] = W + (size_t)(n0 + wn * 64 + t * 16 + lam) * 768 + quad * 8;

    const f32x4 fzero = {0.f, 0.f, 0.f, 0.f};
    f32x4 acc[4][4];
    #pragma unroll
    for (int i = 0; i < 4; i++)
        #pragma unroll
        for (int t = 0; t < 4; t++) acc[i][t] = fzero;

    s16x8 fa[2][4], fb[2][4];
    #pragma unroll
    for (int i = 0; i < 4; i++) fa[0][i] = *(const s16x8*)(Arow[i]);
    #pragma unroll
    for (int t = 0; t < 4; t++) fb[0][t] = *(const s16x8*)(Wrow[t]);

    #pragma unroll
    for (int kc = 0; kc < 24; ++kc) {     // K-chunks of 32
        const int cur = kc & 1, nxt = cur ^ 1;
        if (kc + 1 < 24) {
            #pragma unroll
            for (int i = 0; i < 4; i++) fa[nxt][i] = *(const s16x8*)(Arow[i] + (kc + 1) * 32);
            #pragma unroll
            for (int t = 0; t < 4; t++) fb[nxt][t] = *(const s16x8*)(Wrow[t] + (kc + 1) * 32);
        }
        #pragma unroll
        for (int i = 0; i < 4; i++)
            #pragma unroll
            for (int t = 0; t < 4; t++)
                acc[i][t] = __builtin_amdgcn_mfma_f32_16x16x32_bf16(
                    asbf(fa[cur][i]), asbf(fb[cur][t]), acc[i][t], 0, 0, 0);
    }

    // ---- epilogue ----
    const int nb     = n0 + wn * 64;
    const int region = nb / 768;               // 0=q, 1=k, 2=v
    const int head   = (nb % 768) / 64;
    const int mg0    = m0 + wm * 64;           // 64-aligned -> single batch
    const int b_     = mg0 >> 10;
    const int sg0    = (mg0 & 1023) + strm * 1024;
    short* myE = lE[w];

    float bv[4];
    #pragma unroll
    for (int t = 0; t < 4; t++) bv[t] = bias[nb + t * 16 + lam];
    float gv[4], bb[4];
    if (region < 2) {
        const float* gp = (region == 0) ? (strm ? gqy : gqx) : (strm ? gky : gkx);
        const float* bp = (region == 0) ? (strm ? bqy : bqx) : (strm ? bky : bkx);
        #pragma unroll
        for (int t = 0; t < 4; t++) { gv[t] = gp[t * 16 + lam]; bb[t] = bp[t * 16 + lam]; }
    }

    #pragma unroll
    for (int i = 0; i < 4; i++) {
        #pragma unroll
        for (int reg = 0; reg < 4; reg++) {
            const int lr = i * 16 + quad * 4 + reg;    // local row 0..63
            float v0 = acc[i][0][reg] + bv[0];
            float v1 = acc[i][1][reg] + bv[1];
            float v2 = acc[i][2][reg] + bv[2];
            float v3 = acc[i][3][reg] + bv[3];
            if (region < 2) {
                float s = v0 + v1 + v2 + v3;
                s += __shfl_xor(s, 1); s += __shfl_xor(s, 2);
                s += __shfl_xor(s, 4); s += __shfl_xor(s, 8);
                const float mean = s * (1.f / 64.f);
                const float c0 = v0 - mean, c1 = v1 - mean, c2 = v2 - mean, c3 = v3 - mean;
                float q2 = c0 * c0 + c1 * c1 + c2 * c2 + c3 * c3;
                q2 += __shfl_xor(q2, 1); q2 += __shfl_xor(q2, 2);
                q2 += __shfl_xor(q2, 4); q2 += __shfl_xor(q2, 8);
                const float rs = rsqrtf(q2 * (1.f / 64.f) + 1e-5f);
                v0 = c0 * rs * gv[0] + bb[0];
                v1 = c1 * rs * gv[1] + bb[1];
                v2 = c2 * rs * gv[2] + bb[2];
                v3 = c3 * rs * gv[3] + bb[3];
                myE[lr * 80 + 0 * 16 + lam] = f2bf(v0);   // row-major [s][d]
                myE[lr * 80 + 1 * 16 + lam] = f2bf(v1);
                myE[lr * 80 + 2 * 16 + lam] = f2bf(v2);
                myE[lr * 80 + 3 * 16 + lam] = f2bf(v3);
            } else {
                myE[(0 * 16 + lam) * 80 + lr] = f2bf(v0); // transposed [d][s]
                myE[(1 * 16 + lam) * 80 + lr] = f2bf(v1);
                myE[(2 * 16 + lam) * 80 + lr] = f2bf(v2);
                myE[(3 * 16 + lam) * 80 + lr] = f2bf(v3);
            }
        }
    }

    const int l8 = lane >> 3;
    const int c8 = (lane & 7) * 8;
    if (region < 2) {
        short* dstp = (region == 0 ? Q : K) + ((size_t)(b_ * 12 + head) * 2048 + sg0) * 64;
        #pragma unroll
        for (int j = 0; j < 8; j++) {
            const int rr = j * 8 + l8;
            s16x8 vv = *(const s16x8*)(myE + rr * 80 + c8);
            *(s16x8*)(dstp + (size_t)rr * 64 + c8) = vv;   // 1KB contiguous per instr
        }
    } else {
        short* dstp = Vt + (size_t)(b_ * 12 + head) * 64 * 2048 + sg0;
        #pragma unroll
        for (int j = 0; j < 8; j++) {
            const int dr = j * 8 + l8;
            s16x8 vv = *(const s16x8*)(myE + dr * 80 + c8);
            *(s16x8*)(dstp + (size_t)dr * 2048 + c8) = vv; // 8 x 128B segments
        }
    }
}

// ---------- flash attention (unchanged from round 2/3) ----------

__global__ __launch_bounds__(256, 3) void attn(
    const short* __restrict__ Q, const short* __restrict__ K,
    const short* __restrict__ Vt, short* __restrict__ O)
{
    __shared__ __align__(16) short lK[2][4096];
    __shared__ __align__(16) short lV[2][4096];
    __shared__ __align__(16) short lP[4][1088];
    const int tid  = threadIdx.x;
    const int w    = tid >> 6, lane = tid & 63;
    const int lam  = lane & 15, quad = lane >> 4;
    const int bh   = blockIdx.x;
    const int q0   = blockIdx.y * 128 + w * 32;
    const short* Qb = Q + (size_t)bh * 2048 * 64;
    const short* Kb = K + (size_t)bh * 2048 * 64;
    const short* Vb = Vt + (size_t)bh * 64 * 2048;
    short* myP = lP[w];

    s16x8 aq[2][2];
    #pragma unroll
    for (int qf = 0; qf < 2; qf++)
        #pragma unroll
        for (int c = 0; c < 2; c++)
            aq[qf][c] = *(const s16x8*)(Qb + (size_t)(q0 + qf * 16 + lam) * 64 + c * 32 + quad * 8);

    const f32x4 fzero = {0.f, 0.f, 0.f, 0.f};
    f32x4 o[2][4];
    float lsum[2][4];
    #pragma unroll
    for (int qf = 0; qf < 2; qf++) {
        #pragma unroll
        for (int t = 0; t < 4; t++) o[qf][t] = fzero;
        #pragma unroll
        for (int r = 0; r < 4; r++) lsum[qf][r] = 0.f;
    }

    #define STAGE(s0_, bi_)                                                              \
        do {                                                                             \
            gl_lds16(Kb + (size_t)((s0_) + w * 16 + lam) * 64 + quad * 8,                \
                     &lK[bi_][(0 * 4 + w) * 512]);                                       \
            gl_lds16(Kb + (size_t)((s0_) + w * 16 + lam) * 64 + 32 + quad * 8,           \
                     &lK[bi_][(1 * 4 + w) * 512]);                                       \
            gl_lds16(Vb + (size_t)(w * 16 + lam) * 2048 + (s0_) + quad * 8,              \
                     &lV[bi_][(0 * 4 + w) * 512]);                                       \
            gl_lds16(Vb + (size_t)(w * 16 + lam) * 2048 + (s0_) + 32 + quad * 8,         \
                     &lV[bi_][(1 * 4 + w) * 512]);                                       \
        } while (0)

    STAGE(0, 0);
    __syncthreads();

    const float c1 = 0.18033688011112042f;   // 0.125 * log2(e)
    int bi = 0;
    for (int it = 0; it < 32; ++it) {
        const int s0n = (it + 1) * 64;
        if (s0n < 2048) STAGE(s0n, bi ^ 1);

        const short* cK = lK[bi];
        const short* cV = lV[bi];
        #pragma unroll
        for (int qf = 0; qf < 2; qf++) {
            f32x4 sc[4];
            #pragma unroll
            for (int t = 0; t < 4; t++) sc[t] = fzero;
            #pragma unroll
            for (int t = 0; t < 4; t++) {
                s16x8 k0 = *(const s16x8*)(cK + ((0 * 4 + t) * 512 + lane * 8));
                s16x8 k1 = *(const s16x8*)(cK + ((1 * 4 + t) * 512 + lane * 8));
                sc[t] = __builtin_amdgcn_mfma_f32_16x16x32_bf16(asbf(aq[qf][0]), asbf(k0), sc[t], 0, 0, 0);
                sc[t] = __builtin_amdgcn_mfma_f32_16x16x32_bf16(asbf(aq[qf][1]), asbf(k1), sc[t], 0, 0, 0);
            }
            #pragma unroll
            for (int t = 0; t < 4; t++) {
                const int g = t * 2 + (lam >> 3);
                #pragma unroll
                for (int r = 0; r < 4; r++) {
                    const float p = __builtin_amdgcn_exp2f(__builtin_fmaf(sc[t][r], c1, -30.f));
                    lsum[qf][r] += p;
                    myP[(g * 17 + quad * 4 + r) * 8 + (lam & 7)] = f2bf(p);
                }
            }
            s16x8 ap0 = *(const s16x8*)(myP + (quad * 17 + lam) * 8);
            s16x8 ap1 = *(const s16x8*)(myP + ((4 + quad) * 17 + lam) * 8);
            #pragma unroll
            for (int t = 0; t < 4; t++) {
                s16x8 v0 = *(const s16x8*)(cV + ((0 * 4 + t) * 512 + lane * 8));
                s16x8 v1 = *(const s16x8*)(cV + ((1 * 4 + t) * 512 + lane * 8));
                o[qf][t] = __builtin_amdgcn_mfma_f32_16x16x32_bf16(asbf(ap0), asbf(v0), o[qf][t], 0, 0, 0);
                o[qf][t] = __builtin_amdgcn_mfma_f32_16x16x32_bf16(asbf(ap1), asbf(v1), o[qf][t], 0, 0, 0);
            }
        }
        __syncthreads();
        bi ^= 1;
    }
    #undef STAGE

    const int b_ = bh / 12, h_ = bh % 12;
    #pragma unroll
    for (int qf = 0; qf < 2; qf++) {
        #pragma unroll
        for (int r = 0; r < 4; r++) {
            float l = lsum[qf][r];
            l += __shfl_xor(l, 1); l += __shfl_xor(l, 2);
            l += __shfl_xor(l, 4); l += __shfl_xor(l, 8);
            const float inv = 1.0f / l;
            const int qg = q0 + qf * 16 + quad * 4 + r;
            short* dst = O + ((size_t)(b_ * 2048 + qg)) * 768 + h_ * 64;
            #pragma unroll
            for (int t = 0; t < 4; t++) dst[t * 16 + lam] = f2bf(o[qf][t][r] * inv);
        }
    }
}

// ---------- proj GEMM v4 (per stream: M=4096, N=768, K=768) ----------
// LDS-free, barrier-free, register-pipelined; 64x128 tile; XCD m-stripe swizzle.

__global__ __launch_bounds__(256, 2) void proj_gemm(
    const short* __restrict__ Ob,
    const short* __restrict__ Wpx, const short* __restrict__ Wpy,
    const float* __restrict__ bpx, const float* __restrict__ bpy,
    float* __restrict__ out)
{
    const int tid  = threadIdx.x;
    const int w    = tid >> 6, lane = tid & 63;
    const int lam  = lane & 15, quad = lane >> 4;

    // grid decode: 768 blocks
    const int bid  = blockIdx.x;
    const int xcd  = bid & 7;
    const int slot = bid >> 3;            // 0..95
    const int mloc = slot & 7;
    const int r2   = slot >> 3;           // 0..11
    const int nblk = r2 % 6;
    const int strm = r2 / 6;
    const int m0   = (xcd * 8 + mloc) * 64;
    const int n0   = nblk * 128;

    const short* W    = strm ? Wpy : Wpx;
    const float* bias = strm ? bpy : bpx;
    const int wm = w >> 1, wn = w & 1;

    const short* Arow[2];
    const short* Wrow[4];
    #pragma unroll
    for (int i = 0; i < 2; i++) {
        const int r    = m0 + wm * 32 + i * 16 + lam;
        const int orow = ((r >> 10) * 2048) + (r & 1023) + strm * 1024;
        Arow[i] = Ob + (size_t)orow * 768 + quad * 8;
    }
    #pragma unroll
    for (int t = 0; t < 4; t++)
        Wrow[t] = W + (size_t)(n0 + wn * 64 + t * 16 + lam) * 768 + quad * 8;

    const f32x4 fzero = {0.f, 0.f, 0.f, 0.f};
    f32x4 acc[2][4];
    #pragma unroll
    for (int i = 0; i < 2; i++)
        #pragma unroll
        for (int t = 0; t < 4; t++) acc[i][t] = fzero;

    s16x8 fa[2][2], fb[2][4];
    #pragma unroll
    for (int i = 0; i < 2; i++) fa[0][i] = *(const s16x8*)(Arow[i]);
    #pragma unroll
    for (int t = 0; t < 4; t++) fb[0][t] = *(const s16x8*)(Wrow[t]);

    #pragma unroll
    for (int kc = 0; kc < 24; ++kc) {
        const int cur = kc & 1, nxt = cur ^ 1;
        if (kc + 1 < 24) {
            #pragma unroll
            for (int i = 0; i < 2; i++) fa[nxt][i] = *(const s16x8*)(Arow[i] + (kc + 1) * 32);
            #pragma unroll
            for (int t = 0; t < 4; t++) fb[nxt][t] = *(const s16x8*)(Wrow[t] + (kc + 1) * 32);
        }
        #pragma unroll
        for (int i = 0; i < 2; i++)
            #pragma unroll
            for (int t = 0; t < 4; t++)
                acc[i][t] = __builtin_amdgcn_mfma_f32_16x16x32_bf16(
                    asbf(fa[cur][i]), asbf(fb[cur][t]), acc[i][t], 0, 0, 0);
    }

    const int nb = n0 + wn * 64;
    float bv[4];
    #pragma unroll
    for (int t = 0; t < 4; t++) bv[t] = bias[nb + t * 16 + lam];
    #pragma unroll
    for (int i = 0; i < 2; i++) {
        #pragma unroll
        for (int reg = 0; reg < 4; reg++) {
            const int mg = m0 + wm * 32 + i * 16 + quad * 4 + reg;
            float* dst = out + (size_t)strm * 3145728 + (size_t)mg * 768 + nb;
            #pragma unroll
            for (int t = 0; t < 4; t++) dst[t * 16 + lam] = acc[i][t][reg] + bv[t];
        }
    }
}

// ---------- launch ----------

#define WS_XBF 0
#define WS_YBF 6291456
#define WS_WQX 12582912
#define WS_WQY 16121856
#define WS_WPX 19660800
#define WS_WPY 20840448
#define WS_Q   22020096
#define WS_K   34603008
#define WS_VT  47185920
#define WS_O   59768832

extern "C" void kernel_launch(void* const* d_in, const int* in_sizes, int n_in,
                              void* d_out, int out_size, void* d_ws, size_t ws_size,
                              hipStream_t stream) {
    (void)in_sizes; (void)n_in; (void)out_size; (void)ws_size;
    const float* x       = (const float*)d_in[0];
    const float* y       = (const float*)d_in[1];
    const float* Wqkv_x  = (const float*)d_in[2];
    const float* bqkv_x  = (const float*)d_in[3];
    const float* Wqkv_y  = (const float*)d_in[4];
    const float* bqkv_y  = (const float*)d_in[5];
    const float* Wproj_x = (const float*)d_in[6];
    const float* bproj_x = (const float*)d_in[7];
    const float* Wproj_y = (const float*)d_in[8];
    const float* bproj_y = (const float*)d_in[9];
    const float* gq_x = (const float*)d_in[10];
    const float* bq_x = (const float*)d_in[11];
    const float* gk_x = (const float*)d_in[12];
    const float* bk_x = (const float*)d_in[13];
    const float* gq_y = (const float*)d_in[14];
    const float* bq_y = (const float*)d_in[15];
    const float* gk_y = (const float*)d_in[16];
    const float* bk_y = (const float*)d_in[17];

    char* ws = (char*)d_ws;
    short* xbf = (short*)(ws + WS_XBF);
    short* ybf = (short*)(ws + WS_YBF);
    short* wqx = (short*)(ws + WS_WQX);
    short* wqy = (short*)(ws + WS_WQY);
    short* wpx = (short*)(ws + WS_WPX);
    short* wpy = (short*)(ws + WS_WPY);
    short* Qb  = (short*)(ws + WS_Q);
    short* Kb  = (short*)(ws + WS_K);
    short* Vtb = (short*)(ws + WS_VT);
    short* Ob  = (short*)(ws + WS_O);

    convert_all<<<10752, 256, 0, stream>>>(x, xbf, y, ybf, Wqkv_x, wqx,
                                           Wqkv_y, wqy, Wproj_x, wpx, Wproj_y, wpy);

    qkv_gemm<<<1152, 256, 0, stream>>>(xbf, ybf, wqx, wqy, bqkv_x, bqkv_y,
                                       gq_x, bq_x, gk_x, bk_x,
                                       gq_y, bq_y, gk_y, bk_y,
                                       Qb, Kb, Vtb);

    dim3 g2(48, 16);
    attn<<<g2, 256, 0, stream>>>(Qb, Kb, Vtb, Ob);

    proj_gemm<<<768, 256, 0, stream>>>(Ob, wpx, wpy, bproj_x, bproj_y, (float*)d_out);
}

// Round 5
// 251.675 us; speedup vs baseline: 1.4416x; 1.4416x over previous
//
#include <hip/hip_runtime.h>
#include <stdint.h>

typedef unsigned int u32;
typedef __attribute__((ext_vector_type(8))) __bf16 bf16x8;
typedef __attribute__((ext_vector_type(8))) short s16x8;
typedef __attribute__((ext_vector_type(4))) short s16x4;
typedef __attribute__((ext_vector_type(4))) float f32x4;

// ---------- helpers ----------

__device__ __forceinline__ short f2bf(float f) {
    __bf16 h = (__bf16)f;               // native v_cvt, RNE
    return __builtin_bit_cast(short, h);
}

__device__ __forceinline__ bf16x8 asbf(s16x8 v) {
    return __builtin_bit_cast(bf16x8, v);
}

// async global->LDS, 16B per lane; g is the per-lane address (contiguous here)
__device__ __forceinline__ void gl_lds16(const void* g, void* l) {
    __builtin_amdgcn_global_load_lds((__attribute__((address_space(1))) u32*)g,
                                     (__attribute__((address_space(3))) u32*)l,
                                     16, 0, 0);
}

// Packed tile format (the LDS image, so staging is 1KB-contiguous per instr):
// 128x64 tile = 16 chunks of 512 shorts; chunk ch = c*8+ig (c = k-half, ig = row
// group); within chunk offset = lane*8+j, lane=(quad<<4)|lam, holding element
// [row = ig*16+lam][col = c*32+quad*8+j].
// 64x64 tile = 8 chunks, ch = c*4+ig, same within-chunk rule.

// ---------- pack kernel: fp32 row-major (stride 768) -> packed bf16 tiles ----------
// regions: x 384 | y 384 | wqx 216 | wqy 216 | wpx 72 | wpy 72  (tiles of 128x64)

__global__ __launch_bounds__(256) void pack_tiles(
    const float* __restrict__ x,  short* __restrict__ xP,
    const float* __restrict__ y,  short* __restrict__ yP,
    const float* __restrict__ wqx, short* __restrict__ wqxP,
    const float* __restrict__ wqy, short* __restrict__ wqyP,
    const float* __restrict__ wpx, short* __restrict__ wpxP,
    const float* __restrict__ wpy, short* __restrict__ wpyP)
{
    const int tid  = threadIdx.x;
    const int w    = tid >> 6, lane = tid & 63;
    const int lam  = lane & 15, quad = lane >> 4;

    int t = blockIdx.x;
    const float* src; short* dst;
    if (t < 384)                 { src = x;   dst = xP; }
    else if ((t -= 384) < 384)   { src = y;   dst = yP; }
    else if ((t -= 384) < 216)   { src = wqx; dst = wqxP; }
    else if ((t -= 216) < 216)   { src = wqy; dst = wqyP; }
    else if ((t -= 216) < 72)    { src = wpx; dst = wpxP; }
    else                         { t -= 72;  src = wpy; dst = wpyP; }

    const int kb = t % 12, rb = t / 12;
    const int m0 = rb * 128, k0 = kb * 64;
    short* dtile = dst + (size_t)t * 8192;

    #pragma unroll
    for (int u = 0; u < 2; u++) {
        const int ig = w * 2 + u;
        #pragma unroll
        for (int c = 0; c < 2; c++) {
            const float* sp = src + (size_t)(m0 + ig * 16 + lam) * 768 + k0 + c * 32 + quad * 8;
            f32x4 a = *(const f32x4*)sp;
            f32x4 b = *(const f32x4*)(sp + 4);
            s16x8 o;
            o[0] = f2bf(a.x); o[1] = f2bf(a.y); o[2] = f2bf(a.z); o[3] = f2bf(a.w);
            o[4] = f2bf(b.x); o[5] = f2bf(b.y); o[6] = f2bf(b.z); o[7] = f2bf(b.w);
            *(s16x8*)(dtile + (c * 8 + ig) * 512 + lane * 8) = o;   // 1KB contiguous/chunk
        }
    }
}

// ---------- QKV GEMM (M=4096, N=2304, K=768) + bias + per-head LN ----------
// R2 loop structure (proven), staging from packed tiles: every global_load_lds
// moves a contiguous 1KB. Epilogue writes Q row-major, K/V in packed 64x64 tiles.

__device__ __forceinline__ void stage_qkv(
    const short* __restrict__ At, const short* __restrict__ Wt,
    short* __restrict__ dA, short* __restrict__ dB, int w, int lane)
{
    #pragma unroll
    for (int c = 0; c < 2; c++)
        #pragma unroll
        for (int h = 0; h < 2; h++) {
            const int ch = c * 8 + w + h * 4;
            gl_lds16(At + ch * 512 + lane * 8, dA + ch * 512);
            gl_lds16(Wt + ch * 512 + lane * 8, dB + ch * 512);
        }
}

__global__ __launch_bounds__(256, 2) void qkv_gemm(
    const short* __restrict__ AxP, const short* __restrict__ AyP,
    const short* __restrict__ WxP, const short* __restrict__ WyP,
    const float* __restrict__ biasx, const float* __restrict__ biasy,
    const float* __restrict__ gqx, const float* __restrict__ bqx,
    const float* __restrict__ gkx, const float* __restrict__ bkx,
    const float* __restrict__ gqy, const float* __restrict__ bqy,
    const float* __restrict__ gky, const float* __restrict__ bky,
    short* __restrict__ Q, short* __restrict__ KP, short* __restrict__ VP)
{
    __shared__ union {
        struct { short a[8192]; short b[8192]; } st;     // staging (32 KB)
        short e[4][5120];                                 // epilogue transpose (40 KB)
    } uL;
    const int tid  = threadIdx.x;
    const int w    = tid >> 6, lane = tid & 63;
    const int lam  = lane & 15, quad = lane >> 4;
    const int strm = blockIdx.z;
    const int mblk = blockIdx.x;          // 0..31 (id%8 == mblk%8 -> XCD stripe)
    const int nblk = blockIdx.y;          // 0..17
    const short* AP   = strm ? AyP : AxP;
    const short* WP   = strm ? WyP : WxP;
    const float* bias = strm ? biasy : biasx;
    const int m0 = mblk * 128;
    const int n0 = nblk * 128;
    const int wm = w >> 1, wn = w & 1;

    const f32x4 fzero = {0.f, 0.f, 0.f, 0.f};
    f32x4 acc[4][4];
    #pragma unroll
    for (int i = 0; i < 4; i++)
        #pragma unroll
        for (int t = 0; t < 4; t++) acc[i][t] = fzero;

    for (int kb = 0; kb < 12; ++kb) {
        __syncthreads();
        stage_qkv(AP + (size_t)(mblk * 12 + kb) * 8192,
                  WP + (size_t)(nblk * 12 + kb) * 8192,
                  uL.st.a, uL.st.b, w, lane);
        __syncthreads();
        s16x8 af[2][4], bfr[2][4];
        #pragma unroll
        for (int c = 0; c < 2; c++)
            #pragma unroll
            for (int i = 0; i < 4; i++)
                af[c][i] = *(const s16x8*)(uL.st.a + ((c * 8 + wm * 4 + i) * 64 + lane) * 8);
        #pragma unroll
        for (int c = 0; c < 2; c++)
            #pragma unroll
            for (int t = 0; t < 4; t++)
                bfr[c][t] = *(const s16x8*)(uL.st.b + ((c * 8 + wn * 4 + t) * 64 + lane) * 8);
        #pragma unroll
        for (int c = 0; c < 2; c++)
            #pragma unroll
            for (int i = 0; i < 4; i++)
                #pragma unroll
                for (int t = 0; t < 4; t++)
                    acc[i][t] = __builtin_amdgcn_mfma_f32_16x16x32_bf16(
                        asbf(af[c][i]), asbf(bfr[c][t]), acc[i][t], 0, 0, 0);
    }
    __syncthreads();                       // before reusing staging LDS as uL.e

    // ---- epilogue ----
    const int nb     = n0 + wn * 64;
    const int region = nb / 768;               // 0=q, 1=k, 2=v
    const int head   = (nb % 768) / 64;
    const int mg0    = m0 + wm * 64;           // 64-aligned
    const int b_     = mg0 >> 10;
    const int sg0    = (mg0 & 1023) + strm * 1024;   // concat seq index, 64-aligned
    short* myE = uL.e[w];

    float bv[4];
    #pragma unroll
    for (int t = 0; t < 4; t++) bv[t] = bias[nb + t * 16 + lam];
    float gv[4], bb[4];
    if (region < 2) {
        const float* gp = (region == 0) ? (strm ? gqy : gqx) : (strm ? gky : gkx);
        const float* bp = (region == 0) ? (strm ? bqy : bqx) : (strm ? bky : bkx);
        #pragma unroll
        for (int t = 0; t < 4; t++) { gv[t] = gp[t * 16 + lam]; bb[t] = bp[t * 16 + lam]; }
    }

    #pragma unroll
    for (int i = 0; i < 4; i++) {
        #pragma unroll
        for (int reg = 0; reg < 4; reg++) {
            const int lr = i * 16 + quad * 4 + reg;    // local row 0..63
            float v0 = acc[i][0][reg] + bv[0];
            float v1 = acc[i][1][reg] + bv[1];
            float v2 = acc[i][2][reg] + bv[2];
            float v3 = acc[i][3][reg] + bv[3];
            if (region < 2) {
                float s = v0 + v1 + v2 + v3;
                s += __shfl_xor(s, 1); s += __shfl_xor(s, 2);
                s += __shfl_xor(s, 4); s += __shfl_xor(s, 8);
                const float mean = s * (1.f / 64.f);
                const float c0 = v0 - mean, c1 = v1 - mean, c2 = v2 - mean, c3 = v3 - mean;
                float q2 = c0 * c0 + c1 * c1 + c2 * c2 + c3 * c3;
                q2 += __shfl_xor(q2, 1); q2 += __shfl_xor(q2, 2);
                q2 += __shfl_xor(q2, 4); q2 += __shfl_xor(q2, 8);
                const float rs = rsqrtf(q2 * (1.f / 64.f) + 1e-5f);
                v0 = c0 * rs * gv[0] + bb[0];
                v1 = c1 * rs * gv[1] + bb[1];
                v2 = c2 * rs * gv[2] + bb[2];
                v3 = c3 * rs * gv[3] + bb[3];
                myE[lr * 80 + 0 * 16 + lam] = f2bf(v0);   // row-major [s][d]
                myE[lr * 80 + 1 * 16 + lam] = f2bf(v1);
                myE[lr * 80 + 2 * 16 + lam] = f2bf(v2);
                myE[lr * 80 + 3 * 16 + lam] = f2bf(v3);
            } else {
                myE[(0 * 16 + lam) * 80 + lr] = f2bf(v0); // transposed [d][s]
                myE[(1 * 16 + lam) * 80 + lr] = f2bf(v1);
                myE[(2 * 16 + lam) * 80 + lr] = f2bf(v2);
                myE[(3 * 16 + lam) * 80 + lr] = f2bf(v3);
            }
        }
    }

    if (region == 0) {
        // Q row-major (B,H,2048,64): 1KB-contiguous stores
        const int l8 = lane >> 3, c8 = (lane & 7) * 8;
        short* dstp = Q + ((size_t)(b_ * 12 + head) * 2048 + sg0) * 64;
        #pragma unroll
        for (int j = 0; j < 8; j++) {
            const int rr = j * 8 + l8;
            *(s16x8*)(dstp + (size_t)rr * 64 + c8) = *(const s16x8*)(myE + rr * 80 + c8);
        }
    } else {
        // K/V packed 64x64 tiles: tile = (b*12+h)*32 + sb
        short* dstp = (region == 1 ? KP : VP) +
                      ((size_t)(b_ * 12 + head) * 32 + (sg0 >> 6)) * 4096;
        #pragma unroll
        for (int c = 0; c < 2; c++)
            #pragma unroll
            for (int ig = 0; ig < 4; ig++) {
                s16x8 vv = *(const s16x8*)(myE + (ig * 16 + lam) * 80 + c * 32 + quad * 8);
                *(s16x8*)(dstp + (c * 4 + ig) * 512 + lane * 8) = vv;  // 1KB/chunk
            }
    }
}

// ---------- flash attention: Q row-major; K/V packed tiles; O packed tiles ----------

__global__ __launch_bounds__(256, 3) void attn(
    const short* __restrict__ Q, const short* __restrict__ KP,
    const short* __restrict__ VP, short* __restrict__ OP)
{
    __shared__ union {
        struct { short k[2][4096]; short v[2][4096]; } kv;   // 32 KB staging
        short o[4][2560];                                     // 20 KB epilogue
    } uL;
    __shared__ __align__(16) short lP[4][1088];
    const int tid  = threadIdx.x;
    const int w    = tid >> 6, lane = tid & 63;
    const int lam  = lane & 15, quad = lane >> 4;
    const int bh   = blockIdx.x;
    const int q0   = blockIdx.y * 128 + w * 32;
    const short* Qb  = Q  + (size_t)bh * 2048 * 64;
    const short* KPb = KP + (size_t)bh * 32 * 4096;
    const short* VPb = VP + (size_t)bh * 32 * 4096;
    short* myP = lP[w];

    s16x8 aq[2][2];
    #pragma unroll
    for (int qf = 0; qf < 2; qf++)
        #pragma unroll
        for (int c = 0; c < 2; c++)
            aq[qf][c] = *(const s16x8*)(Qb + (size_t)(q0 + qf * 16 + lam) * 64 + c * 32 + quad * 8);

    const f32x4 fzero = {0.f, 0.f, 0.f, 0.f};
    f32x4 o[2][4];
    float lsum[2][4];
    #pragma unroll
    for (int qf = 0; qf < 2; qf++) {
        #pragma unroll
        for (int t = 0; t < 4; t++) o[qf][t] = fzero;
        #pragma unroll
        for (int r = 0; r < 4; r++) lsum[qf][r] = 0.f;
    }

    // stage s-tile st into buffer bi: 2 K-chunks + 2 V-chunks per wave, all 1KB contiguous
    #define STAGE(st_, bi_)                                                             \
        do {                                                                            \
            const short* kt = KPb + (size_t)(st_) * 4096;                               \
            const short* vt = VPb + (size_t)(st_) * 4096;                               \
            _Pragma("unroll")                                                           \
            for (int u_ = 0; u_ < 2; u_++) {                                            \
                const int ch_ = w * 2 + u_;                                             \
                gl_lds16(kt + ch_ * 512 + lane * 8, &uL.kv.k[bi_][ch_ * 512]);          \
                gl_lds16(vt + ch_ * 512 + lane * 8, &uL.kv.v[bi_][ch_ * 512]);          \
            }                                                                           \
        } while (0)

    STAGE(0, 0);
    __syncthreads();

    const float c1 = 0.18033688011112042f;   // 0.125 * log2(e)
    int bi = 0;
    for (int it = 0; it < 32; ++it) {
        if (it + 1 < 32) STAGE(it + 1, bi ^ 1);

        const short* cK = uL.kv.k[bi];
        const short* cV = uL.kv.v[bi];
        #pragma unroll
        for (int qf = 0; qf < 2; qf++) {
            f32x4 sc[4];
            #pragma unroll
            for (int t = 0; t < 4; t++) sc[t] = fzero;
            #pragma unroll
            for (int t = 0; t < 4; t++) {
                s16x8 k0 = *(const s16x8*)(cK + ((0 * 4 + t) * 512 + lane * 8));
                s16x8 k1 = *(const s16x8*)(cK + ((1 * 4 + t) * 512 + lane * 8));
                sc[t] = __builtin_amdgcn_mfma_f32_16x16x32_bf16(asbf(aq[qf][0]), asbf(k0), sc[t], 0, 0, 0);
                sc[t] = __builtin_amdgcn_mfma_f32_16x16x32_bf16(asbf(aq[qf][1]), asbf(k1), sc[t], 0, 0, 0);
            }
            #pragma unroll
            for (int t = 0; t < 4; t++) {
                const int g = t * 2 + (lam >> 3);
                #pragma unroll
                for (int r = 0; r < 4; r++) {
                    const float p = __builtin_amdgcn_exp2f(__builtin_fmaf(sc[t][r], c1, -30.f));
                    lsum[qf][r] += p;
                    myP[(g * 17 + quad * 4 + r) * 8 + (lam & 7)] = f2bf(p);
                }
            }
            s16x8 ap0 = *(const s16x8*)(myP + (quad * 17 + lam) * 8);
            s16x8 ap1 = *(const s16x8*)(myP + ((4 + quad) * 17 + lam) * 8);
            #pragma unroll
            for (int t = 0; t < 4; t++) {
                s16x8 v0 = *(const s16x8*)(cV + ((0 * 4 + t) * 512 + lane * 8));
                s16x8 v1 = *(const s16x8*)(cV + ((1 * 4 + t) * 512 + lane * 8));
                o[qf][t] = __builtin_amdgcn_mfma_f32_16x16x32_bf16(asbf(ap0), asbf(v0), o[qf][t], 0, 0, 0);
                o[qf][t] = __builtin_amdgcn_mfma_f32_16x16x32_bf16(asbf(ap1), asbf(v1), o[qf][t], 0, 0, 0);
            }
        }
        __syncthreads();
        bi ^= 1;
    }
    #undef STAGE

    // ---- epilogue: normalize, transpose via LDS, write packed O tiles ----
    // (safe to reuse uL: final loop barrier already passed)
    short* myO = uL.o[w];
    #pragma unroll
    for (int qf = 0; qf < 2; qf++) {
        #pragma unroll
        for (int r = 0; r < 4; r++) {
            float l = lsum[qf][r];
            l += __shfl_xor(l, 1); l += __shfl_xor(l, 2);
            l += __shfl_xor(l, 4); l += __shfl_xor(l, 8);
            const float inv = 1.0f / l;
            const int row = qf * 16 + quad * 4 + r;       // 0..31 within wave
            #pragma unroll
            for (int t = 0; t < 4; t++)
                myO[row * 80 + t * 16 + lam] = f2bf(o[qf][t][r] * inv);
        }
    }

    const int b_ = bh / 12, h_ = bh % 12;
    const int strm = q0 >> 10;
    const int s    = q0 & 1023;
    const int sb   = s >> 6;
    short* dstp = OP + (((size_t)((strm * 4 + b_) * 16 + sb)) * 12 + h_) * 4096;
    const int igb = (s & 63) >> 4;                        // 0 or 2
    #pragma unroll
    for (int u = 0; u < 2; u++) {
        const int ig = igb + u;
        #pragma unroll
        for (int c = 0; c < 2; c++) {
            s16x8 vv = *(const s16x8*)(myO + (u * 16 + lam) * 80 + c * 32 + quad * 8);
            *(s16x8*)(dstp + (c * 4 + ig) * 512 + lane * 8) = vv;    // 1KB/chunk
        }
    }
}

// ---------- proj GEMM (per stream: M=4096, N=768, K=768) + bias -> fp32 out ----------
// R2 structure (64x128 tile, dbuf, 3/CU), staging from packed O and packed Wp.

__device__ __forceinline__ void stage_proj(
    const short* __restrict__ Ot, const short* __restrict__ Wt,
    short* __restrict__ dA, short* __restrict__ dB, int w, int lane)
{
    #pragma unroll
    for (int u = 0; u < 2; u++) {
        const int ch = w * 2 + u;
        gl_lds16(Ot + ch * 512 + lane * 8, dA + ch * 512);
    }
    #pragma unroll
    for (int c = 0; c < 2; c++)
        #pragma unroll
        for (int h = 0; h < 2; h++) {
            const int ch = c * 8 + w + h * 4;
            gl_lds16(Wt + ch * 512 + lane * 8, dB + ch * 512);
        }
}

__global__ __launch_bounds__(256, 3) void proj_gemm(
    const short* __restrict__ OP,
    const short* __restrict__ WpxP, const short* __restrict__ WpyP,
    const float* __restrict__ bpx, const float* __restrict__ bpy,
    float* __restrict__ out)
{
    __shared__ __align__(16) short lA[2][4096];   // 64x64 per buffer
    __shared__ __align__(16) short lB[2][8192];   // 128x64 per buffer
    const int tid  = threadIdx.x;
    const int w    = tid >> 6, lane = tid & 63;
    const int lam  = lane & 15, quad = lane >> 4;
    const int strm = blockIdx.z;
    const short* WP   = strm ? WpyP : WpxP;
    const float* bias = strm ? bpy : bpx;
    const int m0 = blockIdx.x * 64;
    const int n0 = blockIdx.y * 128;
    const int wm = w >> 1, wn = w & 1;

    const int b_ = m0 >> 10, sb = (m0 & 1023) >> 6;
    const size_t tA0 = ((size_t)((strm * 4 + b_) * 16 + sb)) * 12;   // + kb
    const size_t tB0 = (size_t)blockIdx.y * 12;                      // + kb

    const f32x4 fzero = {0.f, 0.f, 0.f, 0.f};
    f32x4 acc[2][4];
    #pragma unroll
    for (int i = 0; i < 2; i++)
        #pragma unroll
        for (int t = 0; t < 4; t++) acc[i][t] = fzero;

    stage_proj(OP + tA0 * 4096, WP + tB0 * 8192, lA[0], lB[0], w, lane);
    __syncthreads();

    int bi = 0;
    for (int kb = 0; kb < 12; ++kb) {
        if (kb + 1 < 12)
            stage_proj(OP + (tA0 + kb + 1) * 4096, WP + (tB0 + kb + 1) * 8192,
                       lA[bi ^ 1], lB[bi ^ 1], w, lane);

        const short* cA = lA[bi];
        const short* cB = lB[bi];
        s16x8 af[2][2], bfr[2][4];
        #pragma unroll
        for (int c = 0; c < 2; c++)
            #pragma unroll
            for (int i = 0; i < 2; i++)
                af[c][i] = *(const s16x8*)(cA + ((c * 4 + wm * 2 + i) * 64 + lane) * 8);
        #pragma unroll
        for (int c = 0; c < 2; c++)
            #pragma unroll
            for (int t = 0; t < 4; t++)
                bfr[c][t] = *(const s16x8*)(cB + ((c * 8 + wn * 4 + t) * 64 + lane) * 8);
        #pragma unroll
        for (int c = 0; c < 2; c++)
            #pragma unroll
            for (int i = 0; i < 2; i++)
                #pragma unroll
                for (int t = 0; t < 4; t++)
                    acc[i][t] = __builtin_amdgcn_mfma_f32_16x16x32_bf16(
                        asbf(af[c][i]), asbf(bfr[c][t]), acc[i][t], 0, 0, 0);

        __syncthreads();
        bi ^= 1;
    }

    const int nb = n0 + wn * 64;
    float bv[4];
    #pragma unroll
    for (int t = 0; t < 4; t++) bv[t] = bias[nb + t * 16 + lam];
    #pragma unroll
    for (int i = 0; i < 2; i++) {
        #pragma unroll
        for (int reg = 0; reg < 4; reg++) {
            const int mg = m0 + wm * 32 + i * 16 + quad * 4 + reg;
            float* dst = out + (size_t)strm * 3145728 + (size_t)mg * 768 + nb;
            #pragma unroll
            for (int t = 0; t < 4; t++) dst[t * 16 + lam] = acc[i][t][reg] + bv[t];
        }
    }
}

// ---------- launch ----------

#define WS_XP  0
#define WS_YP  6291456
#define WS_WQX 12582912
#define WS_WQY 16121856
#define WS_WPX 19660800
#define WS_WPY 20840448
#define WS_Q   22020096
#define WS_KP  34603008
#define WS_VP  47185920
#define WS_OP  59768832
// total 72,351,744 bytes

extern "C" void kernel_launch(void* const* d_in, const int* in_sizes, int n_in,
                              void* d_out, int out_size, void* d_ws, size_t ws_size,
                              hipStream_t stream) {
    (void)in_sizes; (void)n_in; (void)out_size; (void)ws_size;
    const float* x       = (const float*)d_in[0];
    const float* y       = (const float*)d_in[1];
    const float* Wqkv_x  = (const float*)d_in[2];
    const float* bqkv_x  = (const float*)d_in[3];
    const float* Wqkv_y  = (const float*)d_in[4];
    const float* bqkv_y  = (const float*)d_in[5];
    const float* Wproj_x = (const float*)d_in[6];
    const float* bproj_x = (const float*)d_in[7];
    const float* Wproj_y = (const float*)d_in[8];
    const float* bproj_y = (const float*)d_in[9];
    const float* gq_x = (const float*)d_in[10];
    const float* bq_x = (const float*)d_in[11];
    const float* gk_x = (const float*)d_in[12];
    const float* bk_x = (const float*)d_in[13];
    const float* gq_y = (const float*)d_in[14];
    const float* bq_y = (const float*)d_in[15];
    const float* gk_y = (const float*)d_in[16];
    const float* bk_y = (const float*)d_in[17];

    char* ws = (char*)d_ws;
    short* xP   = (short*)(ws + WS_XP);
    short* yP   = (short*)(ws + WS_YP);
    short* wqxP = (short*)(ws + WS_WQX);
    short* wqyP = (short*)(ws + WS_WQY);
    short* wpxP = (short*)(ws + WS_WPX);
    short* wpyP = (short*)(ws + WS_WPY);
    short* Qb   = (short*)(ws + WS_Q);
    short* KPb  = (short*)(ws + WS_KP);
    short* VPb  = (short*)(ws + WS_VP);
    short* OPb  = (short*)(ws + WS_OP);

    pack_tiles<<<1344, 256, 0, stream>>>(x, xP, y, yP, Wqkv_x, wqxP,
                                         Wqkv_y, wqyP, Wproj_x, wpxP, Wproj_y, wpyP);

    dim3 g1(32, 18, 2);
    qkv_gemm<<<g1, 256, 0, stream>>>(xP, yP, wqxP, wqyP, bqkv_x, bqkv_y,
                                     gq_x, bq_x, gk_x, bk_x,
                                     gq_y, bq_y, gk_y, bk_y,
                                     Qb, KPb, VPb);

    dim3 g2(48, 16);
    attn<<<g2, 256, 0, stream>>>(Qb, KPb, VPb, OPb);

    dim3 g3(64, 6, 2);
    proj_gemm<<<g3, 256, 0, stream>>>(OPb, wpxP, wpyP, bproj_x, bproj_y, (float*)d_out);
}

// Round 6
// 238.478 us; speedup vs baseline: 1.5213x; 1.0553x over previous
//
#include <hip/hip_runtime.h>
#include <stdint.h>

typedef unsigned int u32;
typedef __attribute__((ext_vector_type(8))) __bf16 bf16x8;
typedef __attribute__((ext_vector_type(8))) short s16x8;
typedef __attribute__((ext_vector_type(4))) short s16x4;
typedef __attribute__((ext_vector_type(4))) float f32x4;

// ---------- helpers ----------

__device__ __forceinline__ short f2bf(float f) {
    __bf16 h = (__bf16)f;               // native v_cvt, RNE
    return __builtin_bit_cast(short, h);
}

__device__ __forceinline__ bf16x8 asbf(s16x8 v) {
    return __builtin_bit_cast(bf16x8, v);
}

// async global->LDS, 16B per lane; g is the per-lane address (contiguous here)
__device__ __forceinline__ void gl_lds16(const void* g, void* l) {
    __builtin_amdgcn_global_load_lds((__attribute__((address_space(1))) u32*)g,
                                     (__attribute__((address_space(3))) u32*)l,
                                     16, 0, 0);
}

// Packed tile format (the LDS image, so every bulk access is 1KB-contiguous):
// 128x64 tile = 16 chunks of 512 shorts; chunk ch = c*8+ig; within chunk
// offset = lane*8+j holding [row = ig*16+(lane&15)][col = c*32+(lane>>4)*8+j].
// 64x64 tile = 8 chunks, ch = c*4+ig, same rule.

// ---------- pack kernel: fp32 row-major (stride 768) -> packed bf16 tiles ----------

__global__ __launch_bounds__(256) void pack_tiles(
    const float* __restrict__ x,  short* __restrict__ xP,
    const float* __restrict__ y,  short* __restrict__ yP,
    const float* __restrict__ wqx, short* __restrict__ wqxP,
    const float* __restrict__ wqy, short* __restrict__ wqyP,
    const float* __restrict__ wpx, short* __restrict__ wpxP,
    const float* __restrict__ wpy, short* __restrict__ wpyP)
{
    const int tid  = threadIdx.x;
    const int w    = tid >> 6, lane = tid & 63;
    const int lam  = lane & 15, quad = lane >> 4;

    int t = blockIdx.x;
    const float* src; short* dst;
    if (t < 384)                 { src = x;   dst = xP; }
    else if ((t -= 384) < 384)   { src = y;   dst = yP; }
    else if ((t -= 384) < 216)   { src = wqx; dst = wqxP; }
    else if ((t -= 216) < 216)   { src = wqy; dst = wqyP; }
    else if ((t -= 216) < 72)    { src = wpx; dst = wpxP; }
    else                         { t -= 72;  src = wpy; dst = wpyP; }

    const int kb = t % 12, rb = t / 12;
    const int m0 = rb * 128, k0 = kb * 64;
    short* dtile = dst + (size_t)t * 8192;

    #pragma unroll
    for (int u = 0; u < 2; u++) {
        const int ig = w * 2 + u;
        #pragma unroll
        for (int c = 0; c < 2; c++) {
            const float* sp = src + (size_t)(m0 + ig * 16 + lam) * 768 + k0 + c * 32 + quad * 8;
            f32x4 a = *(const f32x4*)sp;
            f32x4 b = *(const f32x4*)(sp + 4);
            s16x8 o;
            o[0] = f2bf(a.x); o[1] = f2bf(a.y); o[2] = f2bf(a.z); o[3] = f2bf(a.w);
            o[4] = f2bf(b.x); o[5] = f2bf(b.y); o[6] = f2bf(b.z); o[7] = f2bf(b.w);
            *(s16x8*)(dtile + (c * 8 + ig) * 512 + lane * 8) = o;   // 1KB contiguous/chunk
        }
    }
}

// ---------- QKV GEMM (M=4096, N=2304, K=768) + bias + per-head LN ----------

__device__ __forceinline__ void stage_qkv(
    const short* __restrict__ At, const short* __restrict__ Wt,
    short* __restrict__ dA, short* __restrict__ dB, int w, int lane)
{
    #pragma unroll
    for (int c = 0; c < 2; c++)
        #pragma unroll
        for (int h = 0; h < 2; h++) {
            const int ch = c * 8 + w + h * 4;
            gl_lds16(At + ch * 512 + lane * 8, dA + ch * 512);
            gl_lds16(Wt + ch * 512 + lane * 8, dB + ch * 512);
        }
}

__global__ __launch_bounds__(256, 2) void qkv_gemm(
    const short* __restrict__ AxP, const short* __restrict__ AyP,
    const short* __restrict__ WxP, const short* __restrict__ WyP,
    const float* __restrict__ biasx, const float* __restrict__ biasy,
    const float* __restrict__ gqx, const float* __restrict__ bqx,
    const float* __restrict__ gkx, const float* __restrict__ bkx,
    const float* __restrict__ gqy, const float* __restrict__ bqy,
    const float* __restrict__ gky, const float* __restrict__ bky,
    short* __restrict__ Q, short* __restrict__ KP, short* __restrict__ VP)
{
    __shared__ union {
        struct { short a[8192]; short b[8192]; } st;     // staging (32 KB)
        short e[4][5120];                                 // epilogue transpose (40 KB)
    } uL;
    const int tid  = threadIdx.x;
    const int w    = tid >> 6, lane = tid & 63;
    const int lam  = lane & 15, quad = lane >> 4;
    const int strm = blockIdx.z;
    const int mblk = blockIdx.x;          // id%8 == mblk%8 -> XCD stripe
    const int nblk = blockIdx.y;
    const short* AP   = strm ? AyP : AxP;
    const short* WP   = strm ? WyP : WxP;
    const float* bias = strm ? biasy : biasx;
    const int m0 = mblk * 128;
    const int n0 = nblk * 128;
    const int wm = w >> 1, wn = w & 1;

    const f32x4 fzero = {0.f, 0.f, 0.f, 0.f};
    f32x4 acc[4][4];
    #pragma unroll
    for (int i = 0; i < 4; i++)
        #pragma unroll
        for (int t = 0; t < 4; t++) acc[i][t] = fzero;

    for (int kb = 0; kb < 12; ++kb) {
        __syncthreads();
        stage_qkv(AP + (size_t)(mblk * 12 + kb) * 8192,
                  WP + (size_t)(nblk * 12 + kb) * 8192,
                  uL.st.a, uL.st.b, w, lane);
        __syncthreads();
        s16x8 af[2][4], bfr[2][4];
        #pragma unroll
        for (int c = 0; c < 2; c++)
            #pragma unroll
            for (int i = 0; i < 4; i++)
                af[c][i] = *(const s16x8*)(uL.st.a + ((c * 8 + wm * 4 + i) * 64 + lane) * 8);
        #pragma unroll
        for (int c = 0; c < 2; c++)
            #pragma unroll
            for (int t = 0; t < 4; t++)
                bfr[c][t] = *(const s16x8*)(uL.st.b + ((c * 8 + wn * 4 + t) * 64 + lane) * 8);
        #pragma unroll
        for (int c = 0; c < 2; c++)
            #pragma unroll
            for (int i = 0; i < 4; i++)
                #pragma unroll
                for (int t = 0; t < 4; t++)
                    acc[i][t] = __builtin_amdgcn_mfma_f32_16x16x32_bf16(
                        asbf(af[c][i]), asbf(bfr[c][t]), acc[i][t], 0, 0, 0);
    }
    __syncthreads();                       // before reusing staging LDS as uL.e

    // ---- epilogue ----
    const int nb     = n0 + wn * 64;
    const int region = nb / 768;               // 0=q, 1=k, 2=v
    const int head   = (nb % 768) / 64;
    const int mg0    = m0 + wm * 64;
    const int b_     = mg0 >> 10;
    const int sg0    = (mg0 & 1023) + strm * 1024;   // concat seq index, 64-aligned
    short* myE = uL.e[w];

    float bv[4];
    #pragma unroll
    for (int t = 0; t < 4; t++) bv[t] = bias[nb + t * 16 + lam];
    float gv[4], bb[4];
    if (region < 2) {
        const float* gp = (region == 0) ? (strm ? gqy : gqx) : (strm ? gky : gkx);
        const float* bp = (region == 0) ? (strm ? bqy : bqx) : (strm ? bky : bkx);
        #pragma unroll
        for (int t = 0; t < 4; t++) { gv[t] = gp[t * 16 + lam]; bb[t] = bp[t * 16 + lam]; }
    }

    #pragma unroll
    for (int i = 0; i < 4; i++) {
        #pragma unroll
        for (int reg = 0; reg < 4; reg++) {
            const int lr = i * 16 + quad * 4 + reg;    // local row 0..63
            float v0 = acc[i][0][reg] + bv[0];
            float v1 = acc[i][1][reg] + bv[1];
            float v2 = acc[i][2][reg] + bv[2];
            float v3 = acc[i][3][reg] + bv[3];
            if (region < 2) {
                float s = v0 + v1 + v2 + v3;
                s += __shfl_xor(s, 1); s += __shfl_xor(s, 2);
                s += __shfl_xor(s, 4); s += __shfl_xor(s, 8);
                const float mean = s * (1.f / 64.f);
                const float c0 = v0 - mean, c1 = v1 - mean, c2 = v2 - mean, c3 = v3 - mean;
                float q2 = c0 * c0 + c1 * c1 + c2 * c2 + c3 * c3;
                q2 += __shfl_xor(q2, 1); q2 += __shfl_xor(q2, 2);
                q2 += __shfl_xor(q2, 4); q2 += __shfl_xor(q2, 8);
                const float rs = rsqrtf(q2 * (1.f / 64.f) + 1e-5f);
                v0 = c0 * rs * gv[0] + bb[0];
                v1 = c1 * rs * gv[1] + bb[1];
                v2 = c2 * rs * gv[2] + bb[2];
                v3 = c3 * rs * gv[3] + bb[3];
                myE[lr * 80 + 0 * 16 + lam] = f2bf(v0);   // row-major [s][d]
                myE[lr * 80 + 1 * 16 + lam] = f2bf(v1);
                myE[lr * 80 + 2 * 16 + lam] = f2bf(v2);
                myE[lr * 80 + 3 * 16 + lam] = f2bf(v3);
            } else {
                myE[(0 * 16 + lam) * 80 + lr] = f2bf(v0); // transposed [d][s]
                myE[(1 * 16 + lam) * 80 + lr] = f2bf(v1);
                myE[(2 * 16 + lam) * 80 + lr] = f2bf(v2);
                myE[(3 * 16 + lam) * 80 + lr] = f2bf(v3);
            }
        }
    }

    if (region == 0) {
        const int l8 = lane >> 3, c8 = (lane & 7) * 8;
        short* dstp = Q + ((size_t)(b_ * 12 + head) * 2048 + sg0) * 64;
        #pragma unroll
        for (int j = 0; j < 8; j++) {
            const int rr = j * 8 + l8;
            *(s16x8*)(dstp + (size_t)rr * 64 + c8) = *(const s16x8*)(myE + rr * 80 + c8);
        }
    } else {
        short* dstp = (region == 1 ? KP : VP) +
                      ((size_t)(b_ * 12 + head) * 32 + (sg0 >> 6)) * 4096;
        #pragma unroll
        for (int c = 0; c < 2; c++)
            #pragma unroll
            for (int ig = 0; ig < 4; ig++) {
                s16x8 vv = *(const s16x8*)(myE + (ig * 16 + lam) * 80 + c * 32 + quad * 8);
                *(s16x8*)(dstp + (c * 4 + ig) * 512 + lane * 8) = vv;  // 1KB/chunk
            }
    }
}

// ---------- flash attention v3: barrier-free, LDS only for P ----------
// K/V fragments loaded straight from packed global tiles (1KB-contiguous per
// instr, L1-resident: each 8KB tile reused by 4 waves x 2 q-tiles), shared
// across both q-tiles. No staging, no DMA, no __syncthreads.

__global__ __launch_bounds__(256, 2) void attn(
    const short* __restrict__ Q, const short* __restrict__ KP,
    const short* __restrict__ VP, short* __restrict__ OP)
{
    __shared__ __align__(16) short lP[4][2560];   // per-wave: P roundtrip / O transpose
    const int tid  = threadIdx.x;
    const int w    = tid >> 6, lane = tid & 63;
    const int lam  = lane & 15, quad = lane >> 4;
    const int bh   = blockIdx.x;
    const int q0   = blockIdx.y * 128 + w * 32;
    const short* Qb  = Q  + (size_t)bh * 2048 * 64;
    const short* KPb = KP + (size_t)bh * 32 * 4096;
    const short* VPb = VP + (size_t)bh * 32 * 4096;
    short* myP = lP[w];

    s16x8 aq[2][2];
    #pragma unroll
    for (int qf = 0; qf < 2; qf++)
        #pragma unroll
        for (int c = 0; c < 2; c++)
            aq[qf][c] = *(const s16x8*)(Qb + (size_t)(q0 + qf * 16 + lam) * 64 + c * 32 + quad * 8);

    const f32x4 fzero = {0.f, 0.f, 0.f, 0.f};
    f32x4 o[2][4];
    float lsum[2][4];
    #pragma unroll
    for (int qf = 0; qf < 2; qf++) {
        #pragma unroll
        for (int t = 0; t < 4; t++) o[qf][t] = fzero;
        #pragma unroll
        for (int r = 0; r < 4; r++) lsum[qf][r] = 0.f;
    }

    const float c1 = 0.18033688011112042f;   // 0.125 * log2(e)

    for (int it = 0; it < 32; ++it) {
        const short* kt = KPb + (size_t)it * 4096;
        const short* vt = VPb + (size_t)it * 4096;

        // K fragments: whole 64x64 tile into regs (8 x 1KB contiguous loads)
        s16x8 kf[4][2];
        #pragma unroll
        for (int t = 0; t < 4; t++) {
            kf[t][0] = *(const s16x8*)(kt + (0 * 4 + t) * 512 + lane * 8);
            kf[t][1] = *(const s16x8*)(kt + (1 * 4 + t) * 512 + lane * 8);
        }
        // V fragments issued early; consumed after softmax (latency hidden)
        s16x8 vf[4][2];
        #pragma unroll
        for (int t = 0; t < 4; t++) {
            vf[t][0] = *(const s16x8*)(vt + (0 * 4 + t) * 512 + lane * 8);
            vf[t][1] = *(const s16x8*)(vt + (1 * 4 + t) * 512 + lane * 8);
        }

        // ---- scores (K-frags shared across both q-tiles) ----
        f32x4 sc[2][4];
        #pragma unroll
        for (int qf = 0; qf < 2; qf++)
            #pragma unroll
            for (int t = 0; t < 4; t++) sc[qf][t] = fzero;
        #pragma unroll
        for (int t = 0; t < 4; t++)
            #pragma unroll
            for (int qf = 0; qf < 2; qf++) {
                sc[qf][t] = __builtin_amdgcn_mfma_f32_16x16x32_bf16(
                    asbf(aq[qf][0]), asbf(kf[t][0]), sc[qf][t], 0, 0, 0);
                sc[qf][t] = __builtin_amdgcn_mfma_f32_16x16x32_bf16(
                    asbf(aq[qf][1]), asbf(kf[t][1]), sc[qf][t], 0, 0, 0);
            }

        // ---- softmax + P roundtrip (per-wave LDS, in-order DS pipe) ----
        s16x8 ap[2][2];
        #pragma unroll
        for (int qf = 0; qf < 2; qf++) {
            #pragma unroll
            for (int t = 0; t < 4; t++) {
                const int g = t * 2 + (lam >> 3);
                #pragma unroll
                for (int r = 0; r < 4; r++) {
                    const float p = __builtin_amdgcn_exp2f(__builtin_fmaf(sc[qf][t][r], c1, -30.f));
                    lsum[qf][r] += p;
                    myP[(g * 17 + quad * 4 + r) * 8 + (lam & 7)] = f2bf(p);
                }
            }
            ap[qf][0] = *(const s16x8*)(myP + (quad * 17 + lam) * 8);
            ap[qf][1] = *(const s16x8*)(myP + ((4 + quad) * 17 + lam) * 8);
        }

        // ---- O += P @ V (V-frags shared across both q-tiles) ----
        #pragma unroll
        for (int t = 0; t < 4; t++)
            #pragma unroll
            for (int qf = 0; qf < 2; qf++) {
                o[qf][t] = __builtin_amdgcn_mfma_f32_16x16x32_bf16(
                    asbf(ap[qf][0]), asbf(vf[t][0]), o[qf][t], 0, 0, 0);
                o[qf][t] = __builtin_amdgcn_mfma_f32_16x16x32_bf16(
                    asbf(ap[qf][1]), asbf(vf[t][1]), o[qf][t], 0, 0, 0);
            }
    }

    // ---- epilogue: normalize, transpose via per-wave LDS, packed O tiles ----
    short* myO = lP[w];
    #pragma unroll
    for (int qf = 0; qf < 2; qf++) {
        #pragma unroll
        for (int r = 0; r < 4; r++) {
            float l = lsum[qf][r];
            l += __shfl_xor(l, 1); l += __shfl_xor(l, 2);
            l += __shfl_xor(l, 4); l += __shfl_xor(l, 8);
            const float inv = 1.0f / l;
            const int row = qf * 16 + quad * 4 + r;       // 0..31 within wave
            #pragma unroll
            for (int t = 0; t < 4; t++)
                myO[row * 80 + t * 16 + lam] = f2bf(o[qf][t][r] * inv);
        }
    }

    const int b_ = bh / 12, h_ = bh % 12;
    const int strm = q0 >> 10;
    const int s    = q0 & 1023;
    const int sb   = s >> 6;
    short* dstp = OP + (((size_t)((strm * 4 + b_) * 16 + sb)) * 12 + h_) * 4096;
    const int igb = (s & 63) >> 4;                        // 0 or 2
    #pragma unroll
    for (int u = 0; u < 2; u++) {
        const int ig = igb + u;
        #pragma unroll
        for (int c = 0; c < 2; c++) {
            s16x8 vv = *(const s16x8*)(myO + (u * 16 + lam) * 80 + c * 32 + quad * 8);
            *(s16x8*)(dstp + (c * 4 + ig) * 512 + lane * 8) = vv;    // 1KB/chunk
        }
    }
}

// ---------- proj GEMM (per stream: M=4096, N=768, K=768) + bias -> fp32 out ----------

__device__ __forceinline__ void stage_proj(
    const short* __restrict__ Ot, const short* __restrict__ Wt,
    short* __restrict__ dA, short* __restrict__ dB, int w, int lane)
{
    #pragma unroll
    for (int u = 0; u < 2; u++) {
        const int ch = w * 2 + u;
        gl_lds16(Ot + ch * 512 + lane * 8, dA + ch * 512);
    }
    #pragma unroll
    for (int c = 0; c < 2; c++)
        #pragma unroll
        for (int h = 0; h < 2; h++) {
            const int ch = c * 8 + w + h * 4;
            gl_lds16(Wt + ch * 512 + lane * 8, dB + ch * 512);
        }
}

__global__ __launch_bounds__(256, 3) void proj_gemm(
    const short* __restrict__ OP,
    const short* __restrict__ WpxP, const short* __restrict__ WpyP,
    const float* __restrict__ bpx, const float* __restrict__ bpy,
    float* __restrict__ out)
{
    __shared__ __align__(16) short lA[2][4096];
    __shared__ __align__(16) short lB[2][8192];
    const int tid  = threadIdx.x;
    const int w    = tid >> 6, lane = tid & 63;
    const int lam  = lane & 15, quad = lane >> 4;
    const int strm = blockIdx.z;
    const short* WP   = strm ? WpyP : WpxP;
    const float* bias = strm ? bpy : bpx;
    const int m0 = blockIdx.x * 64;
    const int n0 = blockIdx.y * 128;
    const int wm = w >> 1, wn = w & 1;

    const int b_ = m0 >> 10, sb = (m0 & 1023) >> 6;
    const size_t tA0 = ((size_t)((strm * 4 + b_) * 16 + sb)) * 12;
    const size_t tB0 = (size_t)blockIdx.y * 12;

    const f32x4 fzero = {0.f, 0.f, 0.f, 0.f};
    f32x4 acc[2][4];
    #pragma unroll
    for (int i = 0; i < 2; i++)
        #pragma unroll
        for (int t = 0; t < 4; t++) acc[i][t] = fzero;

    stage_proj(OP + tA0 * 4096, WP + tB0 * 8192, lA[0], lB[0], w, lane);
    __syncthreads();

    int bi = 0;
    for (int kb = 0; kb < 12; ++kb) {
        if (kb + 1 < 12)
            stage_proj(OP + (tA0 + kb + 1) * 4096, WP + (tB0 + kb + 1) * 8192,
                       lA[bi ^ 1], lB[bi ^ 1], w, lane);

        const short* cA = lA[bi];
        const short* cB = lB[bi];
        s16x8 af[2][2], bfr[2][4];
        #pragma unroll
        for (int c = 0; c < 2; c++)
            #pragma unroll
            for (int i = 0; i < 2; i++)
                af[c][i] = *(const s16x8*)(cA + ((c * 4 + wm * 2 + i) * 64 + lane) * 8);
        #pragma unroll
        for (int c = 0; c < 2; c++)
            #pragma unroll
            for (int t = 0; t < 4; t++)
                bfr[c][t] = *(const s16x8*)(cB + ((c * 8 + wn * 4 + t) * 64 + lane) * 8);
        #pragma unroll
        for (int c = 0; c < 2; c++)
            #pragma unroll
            for (int i = 0; i < 2; i++)
                #pragma unroll
                for (int t = 0; t < 4; t++)
                    acc[i][t] = __builtin_amdgcn_mfma_f32_16x16x32_bf16(
                        asbf(af[c][i]), asbf(bfr[c][t]), acc[i][t], 0, 0, 0);

        __syncthreads();
        bi ^= 1;
    }

    const int nb = n0 + wn * 64;
    float bv[4];
    #pragma unroll
    for (int t = 0; t < 4; t++) bv[t] = bias[nb + t * 16 + lam];
    #pragma unroll
    for (int i = 0; i < 2; i++) {
        #pragma unroll
        for (int reg = 0; reg < 4; reg++) {
            const int mg = m0 + wm * 32 + i * 16 + quad * 4 + reg;
            float* dst = out + (size_t)strm * 3145728 + (size_t)mg * 768 + nb;
            #pragma unroll
            for (int t = 0; t < 4; t++) dst[t * 16 + lam] = acc[i][t][reg] + bv[t];
        }
    }
}

// ---------- launch ----------

#define WS_XP  0
#define WS_YP  6291456
#define WS_WQX 12582912
#define WS_WQY 16121856
#define WS_WPX 19660800
#define WS_WPY 20840448
#define WS_Q   22020096
#define WS_KP  34603008
#define WS_VP  47185920
#define WS_OP  59768832

extern "C" void kernel_launch(void* const* d_in, const int* in_sizes, int n_in,
                              void* d_out, int out_size, void* d_ws, size_t ws_size,
                              hipStream_t stream) {
    (void)in_sizes; (void)n_in; (void)out_size; (void)ws_size;
    const float* x       = (const float*)d_in[0];
    const float* y       = (const float*)d_in[1];
    const float* Wqkv_x  = (const float*)d_in[2];
    const float* bqkv_x  = (const float*)d_in[3];
    const float* Wqkv_y  = (const float*)d_in[4];
    const float* bqkv_y  = (const float*)d_in[5];
    const float* Wproj_x = (const float*)d_in[6];
    const float* bproj_x = (const float*)d_in[7];
    const float* Wproj_y = (const float*)d_in[8];
    const float* bproj_y = (const float*)d_in[9];
    const float* gq_x = (const float*)d_in[10];
    const float* bq_x = (const float*)d_in[11];
    const float* gk_x = (const float*)d_in[12];
    const float* bk_x = (const float*)d_in[13];
    const float* gq_y = (const float*)d_in[14];
    const float* bq_y = (const float*)d_in[15];
    const float* gk_y = (const float*)d_in[16];
    const float* bk_y = (const float*)d_in[17];

    char* ws = (char*)d_ws;
    short* xP   = (short*)(ws + WS_XP);
    short* yP   = (short*)(ws + WS_YP);
    short* wqxP = (short*)(ws + WS_WQX);
    short* wqyP = (short*)(ws + WS_WQY);
    short* wpxP = (short*)(ws + WS_WPX);
    short* wpyP = (short*)(ws + WS_WPY);
    short* Qb   = (short*)(ws + WS_Q);
    short* KPb  = (short*)(ws + WS_KP);
    short* VPb  = (short*)(ws + WS_VP);
    short* OPb  = (short*)(ws + WS_OP);

    pack_tiles<<<1344, 256, 0, stream>>>(x, xP, y, yP, Wqkv_x, wqxP,
                                         Wqkv_y, wqyP, Wproj_x, wpxP, Wproj_y, wpyP);

    dim3 g1(32, 18, 2);
    qkv_gemm<<<g1, 256, 0, stream>>>(xP, yP, wqxP, wqyP, bqkv_x, bqkv_y,
                                     gq_x, bq_x, gk_x, bk_x,
                                     gq_y, bq_y, gk_y, bk_y,
                                     Qb, KPb, VPb);

    dim3 g2(48, 16);
    attn<<<g2, 256, 0, stream>>>(Qb, KPb, VPb, OPb);

    dim3 g3(64, 6, 2);
    proj_gemm<<<g3, 256, 0, stream>>>(OPb, wpxP, wpyP, bproj_x, bproj_y, (float*)d_out);
}